// Round 2
// baseline (13604.936 us; speedup 1.0000x reference)
//
#include <hip/hip_runtime.h>

#define NA   50000
#define NP   15000
#define EA   200000
#define EP   60000
#define EC   50000
#define HID  300
#define CH   50000   // edge-chunk rows (even, so pair e^1 stays in-chunk)

#define CDIV(a,b) (((a)+(b)-1)/(b))

// ---------------------------------------------------------------------------
// Tiled fp32 GEMM: C[M,N] = act( (accum?C:0) + A[M,K]@B[K,N] + bias + res )
// 64x64 tile, 256 threads, 4x4 micro-tile per thread, TK=16.
// ---------------------------------------------------------------------------
__global__ __launch_bounds__(256)
void gemm_kernel(const float* __restrict__ A, const float* __restrict__ B,
                 const float* __restrict__ bias, const float* __restrict__ res,
                 float* __restrict__ C, int M, int N, int K, int accum, int relu)
{
    __shared__ float As[16][68];   // [k][m], +4 pad keeps float4 alignment
    __shared__ float Bs[16][68];   // [k][n]
    const int tid  = threadIdx.x;
    const int tx   = tid & 15;     // col group
    const int ty   = tid >> 4;     // row group
    const int row0 = blockIdx.y * 64;
    const int col0 = blockIdx.x * 64;
    float acc[4][4] = {{0.f}};

    for (int k0 = 0; k0 < K; k0 += 16) {
#pragma unroll
        for (int p = 0; p < 4; ++p) {          // A tile: 64 rows x 16 k
            int idx = p * 256 + tid;
            int m   = idx >> 4;
            int kk  = idx & 15;
            int gr  = row0 + m;
            int gk  = k0 + kk;
            As[kk][m] = (gr < M && gk < K) ? A[(size_t)gr * K + gk] : 0.f;
        }
#pragma unroll
        for (int p = 0; p < 4; ++p) {          // B tile: 16 k x 64 cols
            int idx = p * 256 + tid;
            int kk  = idx >> 6;
            int n   = idx & 63;
            int gk  = k0 + kk;
            int gc  = col0 + n;
            Bs[kk][n] = (gk < K && gc < N) ? B[(size_t)gk * N + gc] : 0.f;
        }
        __syncthreads();
#pragma unroll
        for (int kk = 0; kk < 16; ++kk) {
            float4 a4 = *(const float4*)&As[kk][ty * 4];
            float4 b4 = *(const float4*)&Bs[kk][tx * 4];
            float av[4] = {a4.x, a4.y, a4.z, a4.w};
            float bv[4] = {b4.x, b4.y, b4.z, b4.w};
#pragma unroll
            for (int i = 0; i < 4; ++i)
#pragma unroll
                for (int j = 0; j < 4; ++j)
                    acc[i][j] = fmaf(av[i], bv[j], acc[i][j]);
        }
        __syncthreads();
    }

#pragma unroll
    for (int i = 0; i < 4; ++i) {
        int r = row0 + ty * 4 + i;
        if (r >= M) continue;
#pragma unroll
        for (int j = 0; j < 4; ++j) {
            int c = col0 + tx * 4 + j;
            if (c >= N) continue;
            size_t o = (size_t)r * N + c;
            float v = acc[i][j];
            if (bias)  v += bias[c];
            if (res)   v += res[o];
            if (accum) v += C[o];
            if (relu)  v = fmaxf(v, 0.f);
            C[o] = v;
        }
    }
}

// ---------------------------------------------------------------------------
// Elementwise / scatter kernels
// ---------------------------------------------------------------------------
__global__ void deg_kernel(const int* __restrict__ dst, float* __restrict__ deg, int E)
{
    int t = blockIdx.x * blockDim.x + threadIdx.x;
    if (t < E) unsafeAtomicAdd(&deg[dst[t]], 1.f);
}

// s[e,h] = dot(q[dst[e],h,:], k[e,h,:]) / sqrt(75); es = exp(s); den[dst,h] += es
__global__ void attn_score_kernel(const float* __restrict__ q, const float* __restrict__ k,
                                  const int* __restrict__ dst,
                                  float* __restrict__ es, float* __restrict__ den, int E)
{
    int t = blockIdx.x * blockDim.x + threadIdx.x;
    if (t >= E * 4) return;
    int e = t >> 2;
    int h = t & 3;
    int d = dst[e];
    const float* qp = q + (size_t)d * HID + h * 75;
    const float* kp = k + (size_t)e * HID + h * 75;
    float s = 0.f;
#pragma unroll 5
    for (int i = 0; i < 75; ++i) s = fmaf(qp[i], kp[i], s);
    float ex = expf(s * 0.11547005383792516f);   // 1/sqrt(75)
    es[t] = ex;
    unsafeAtomicAdd(&den[d * 4 + h], ex);
}

// ctx[dst[e], d] += (es[e,h]/den[dst[e],h]) * v[e,d],  h = d/75
__global__ void attn_ctx_kernel(const float* __restrict__ v, const float* __restrict__ es,
                                const float* __restrict__ den, const int* __restrict__ dst,
                                float* __restrict__ ctx, int E)
{
    int t = blockIdx.x * blockDim.x + threadIdx.x;
    if (t >= E * HID) return;
    int e = t / HID;
    int dc = t - e * HID;
    int h = dc / 75;
    int d = dst[e];
    float w = es[e * 4 + h] / den[d * 4 + h];
    unsafeAtomicAdd(&ctx[(size_t)d * HID + dc], w * v[t]);
}

// feat += out where deg>0
__global__ void masked_residual_kernel(const float* __restrict__ outp,
                                       const float* __restrict__ deg,
                                       float* __restrict__ feat, int total)
{
    int t = blockIdx.x * blockDim.x + threadIdx.x;
    if (t >= total) return;
    int n = t / HID;
    if (deg[n] > 0.f) feat[t] += outp[t];
}

// m_local[el,d] = feat[src[c0+el],d] - h[(c0+el)^1,d]   (global reverse pair)
__global__ void gather_sub_kernel(const float* __restrict__ feat, const float* __restrict__ h,
                                  const int* __restrict__ src, float* __restrict__ m,
                                  int mrows, int c0)
{
    int t = blockIdx.x * blockDim.x + threadIdx.x;
    if (t >= mrows * HID) return;
    int el = t / HID;
    int d  = t - el * HID;
    int ge = c0 + el;
    m[t] = feat[(size_t)src[ge] * HID + d] - h[(size_t)(ge ^ 1) * HID + d];
}

// mail[dst[e],d] += h[e,d]
__global__ void mail_sum_kernel(const float* __restrict__ h, const int* __restrict__ dst,
                                float* __restrict__ mail, int E)
{
    int t = blockIdx.x * blockDim.x + threadIdx.x;
    if (t >= E * HID) return;
    int e = t / HID;
    int d = t - e * HID;
    unsafeAtomicAdd(&mail[(size_t)dst[e] * HID + d], h[t]);
}

// mail[dst[e],d] += feat[src[e],d]
__global__ void mail_gather_kernel(const float* __restrict__ feat, const int* __restrict__ src,
                                   const int* __restrict__ dst, float* __restrict__ mail, int E)
{
    int t = blockIdx.x * blockDim.x + threadIdx.x;
    if (t >= E * HID) return;
    int e = t / HID;
    int d = t - e * HID;
    unsafeAtomicAdd(&mail[(size_t)dst[e] * HID + d], feat[(size_t)src[e] * HID + d]);
}

// out = deg>0 ? newv : oldv
__global__ void select_kernel(const float* __restrict__ newv, const float* __restrict__ oldv,
                              const float* __restrict__ deg, float* __restrict__ outp, int total)
{
    int t = blockIdx.x * blockDim.x + threadIdx.x;
    if (t >= total) return;
    int n = t / HID;
    outp[t] = (deg[n] > 0.f) ? newv[t] : oldv[t];
}

// ---------------------------------------------------------------------------
// Host-side helpers
// ---------------------------------------------------------------------------
static void gemm(const float* A, const float* B, const float* bias, const float* res,
                 float* C, int M, int N, int K, int accum, int relu, hipStream_t s)
{
    dim3 grid(CDIV(N, 64), CDIV(M, 64));
    gemm_kernel<<<grid, 256, 0, s>>>(A, B, bias, res, C, M, N, K, accum, relu);
}

// attention pass; Q: n*HID, KV: CH*HID (chunk buf), CTX: n*HID
static void run_attn(float* feat, const float* h, const int* dst, int n, int E,
                     const float* Wq, const float* bq, const float* Wk, const float* bk,
                     const float* Wv, const float* bv, const float* Wo, const float* bo,
                     const float* deg,
                     float* Q, float* KV, float* CTX, float* ES, float* DEN,
                     hipStream_t stream)
{
    gemm(feat, Wq, bq, nullptr, Q, n, HID, HID, 0, 0, stream);         // q
    hipMemsetAsync(DEN, 0, (size_t)n * 4 * sizeof(float), stream);
    for (int c0 = 0; c0 < E; c0 += CH) {                               // k + scores
        int m = (E - c0 < CH) ? (E - c0) : CH;
        gemm(h + (size_t)c0 * HID, Wk, bk, nullptr, KV, m, HID, HID, 0, 0, stream);
        attn_score_kernel<<<CDIV(m * 4, 256), 256, 0, stream>>>(
            Q, KV, dst + c0, ES + (size_t)c0 * 4, DEN, m);
    }
    hipMemsetAsync(CTX, 0, (size_t)n * HID * sizeof(float), stream);
    for (int c0 = 0; c0 < E; c0 += CH) {                               // v + aggregate
        int m = (E - c0 < CH) ? (E - c0) : CH;
        gemm(h + (size_t)c0 * HID, Wv, bv, nullptr, KV, m, HID, HID, 0, 0, stream);
        attn_ctx_kernel<<<CDIV(m * HID, 256), 256, 0, stream>>>(
            KV, ES + (size_t)c0 * 4, DEN, dst + c0, CTX, m);
    }
    gemm(CTX, Wo, bo, nullptr, Q, n, HID, HID, 0, 0, stream);          // out = ctx@Wo+bo
    masked_residual_kernel<<<CDIV(n * HID, 256), 256, 0, stream>>>(Q, deg, feat, n * HID);
}

// h = relu(x + (feat[src] - h_rev) @ W + b), chunked through MB (CH rows)
static void run_mp(const float* feat, float* h, const float* x, const int* src,
                   const float* W, const float* b, int E, float* MB, hipStream_t stream)
{
    for (int c0 = 0; c0 < E; c0 += CH) {
        int m = (E - c0 < CH) ? (E - c0) : CH;
        gather_sub_kernel<<<CDIV(m * HID, 256), 256, 0, stream>>>(feat, h, src, MB, m, c0);
        gemm(MB, W, b, x + (size_t)c0 * HID, h + (size_t)c0 * HID, m, HID, HID, 0, 1, stream);
    }
}

static void last_pass(const float* mail, const float* mid, const float* first,
                      const float* W, const float* b, const float* deg,
                      const float* oldv, float* tmp, float* outp, int n, hipStream_t stream)
{
    // concat([mail, mid, first]) @ W + b == mail@W0 + mid@W1 + first@W2 + b
    gemm(mail,  W,             b,       nullptr, tmp, n, HID, HID, 0, 0, stream);
    gemm(mid,   W + 300 * HID, nullptr, nullptr, tmp, n, HID, HID, 1, 0, stream);
    gemm(first, W + 600 * HID, nullptr, nullptr, tmp, n, HID, HID, 1, 0, stream);
    select_kernel<<<CDIV(n * HID, 256), 256, 0, stream>>>(tmp, oldv, deg, outp, n * HID);
}

// ---------------------------------------------------------------------------
extern "C" void kernel_launch(void* const* d_in, const int* in_sizes, int n_in,
                              void* d_out, int out_size, void* d_ws, size_t ws_size,
                              hipStream_t stream)
{
    (void)in_sizes; (void)n_in; (void)out_size; (void)ws_size;

    const float* f_a      = (const float*)d_in[0];
    const float* f_p      = (const float*)d_in[1];
    const float* f_junc_a = (const float*)d_in[2];
    const float* f_junc_p = (const float*)d_in[3];
    const float* x_aba    = (const float*)d_in[4];
    const float* x_prp    = (const float*)d_in[5];
    const float* Wq_aba = (const float*)d_in[6];  const float* bq_aba = (const float*)d_in[7];
    const float* Wk_aba = (const float*)d_in[8];  const float* bk_aba = (const float*)d_in[9];
    const float* Wv_aba = (const float*)d_in[10]; const float* bv_aba = (const float*)d_in[11];
    const float* Wo_aba = (const float*)d_in[12]; const float* bo_aba = (const float*)d_in[13];
    const float* mpW_aba = (const float*)d_in[14]; const float* mpb_aba = (const float*)d_in[15];
    const float* Wq_prp = (const float*)d_in[16]; const float* bq_prp = (const float*)d_in[17];
    const float* Wk_prp = (const float*)d_in[18]; const float* bk_prp = (const float*)d_in[19];
    const float* Wv_prp = (const float*)d_in[20]; const float* bv_prp = (const float*)d_in[21];
    const float* Wo_prp = (const float*)d_in[22]; const float* bo_prp = (const float*)d_in[23];
    const float* mpW_prp = (const float*)d_in[24]; const float* mpb_prp = (const float*)d_in[25];
    const float* Wlast_a = (const float*)d_in[26]; const float* blast_a = (const float*)d_in[27];
    const float* Wlast_p = (const float*)d_in[28]; const float* blast_p = (const float*)d_in[29];
    const int* a_src  = (const int*)d_in[30]; const int* a_dst  = (const int*)d_in[31];
    const int* p_src  = (const int*)d_in[32]; const int* p_dst  = (const int*)d_in[33];
    const int* ap_src = (const int*)d_in[34]; const int* ap_dst = (const int*)d_in[35];
    const int* pa_src = (const int*)d_in[36]; const int* pa_dst = (const int*)d_in[37];

    float* out = (float*)d_out;

    // ---- workspace layout (floats), ~575 MB total ----
    float* ws = (float*)d_ws;
    size_t off = 0;
    auto alloc = [&](size_t nf) {
        float* p = ws + off;
        off += (nf + 255) & ~(size_t)255;       // 1 KiB-aligned buffers
        return p;
    };
    float* FA   = alloc((size_t)NA * HID);      // 15.0 M floats
    float* FP   = alloc((size_t)NP * HID);      //  4.5 M
    float* HA   = alloc((size_t)EA * HID);      // 60.0 M
    float* HP   = alloc((size_t)EP * HID);      // 18.0 M
    float* Q    = alloc((size_t)NA * HID);      // 15.0 M  q / o-proj tmp
    float* KV   = alloc((size_t)CH * HID);      // 15.0 M  k/v/msg chunk buf
    float* CTX  = alloc((size_t)NA * HID);      // 15.0 M  ctx / mailbox / gemm tmp
    float* ES   = alloc((size_t)EA * 4);        //  0.8 M
    float* DEN  = alloc((size_t)NA * 4);        //  0.2 M
    float* DEGA = alloc(NA);
    float* DEGP = alloc(NP);
    float* DEGPA= alloc(NA);
    float* DEGAP= alloc(NP);
    // total ≈ 143.7 M floats ≈ 575 MB

    // ---- degrees (recomputed every call; ws is re-poisoned by harness) ----
    hipMemsetAsync(DEGA, 0, NA * sizeof(float), stream);
    hipMemsetAsync(DEGP, 0, NP * sizeof(float), stream);
    hipMemsetAsync(DEGPA, 0, NA * sizeof(float), stream);
    hipMemsetAsync(DEGAP, 0, NP * sizeof(float), stream);
    deg_kernel<<<CDIV(EA, 256), 256, 0, stream>>>(a_dst, DEGA, EA);
    deg_kernel<<<CDIV(EP, 256), 256, 0, stream>>>(p_dst, DEGP, EP);
    deg_kernel<<<CDIV(EC, 256), 256, 0, stream>>>(pa_dst, DEGPA, EC);
    deg_kernel<<<CDIV(EC, 256), 256, 0, stream>>>(ap_dst, DEGAP, EC);

    // ---- init state ----
    hipMemcpyAsync(FA, f_a,   (size_t)NA * HID * sizeof(float), hipMemcpyDeviceToDevice, stream);
    hipMemcpyAsync(FP, f_p,   (size_t)NP * HID * sizeof(float), hipMemcpyDeviceToDevice, stream);
    hipMemcpyAsync(HA, x_aba, (size_t)EA * HID * sizeof(float), hipMemcpyDeviceToDevice, stream);
    hipMemcpyAsync(HP, x_prp, (size_t)EP * HID * sizeof(float), hipMemcpyDeviceToDevice, stream);

    // ---- DEPTH-1 = 2 message-passing iterations ----
    for (int i = 0; i < 2; ++i) {
        run_attn(FA, HA, a_dst, NA, EA,
                 Wq_aba, bq_aba, Wk_aba, bk_aba, Wv_aba, bv_aba, Wo_aba, bo_aba,
                 DEGA, Q, KV, CTX, ES, DEN, stream);
        run_attn(FP, HP, p_dst, NP, EP,
                 Wq_prp, bq_prp, Wk_prp, bk_prp, Wv_prp, bv_prp, Wo_prp, bo_prp,
                 DEGP, Q, KV, CTX, ES, DEN, stream);
        run_mp(FA, HA, x_aba, a_src, mpW_aba + (size_t)i * HID * HID, mpb_aba + i * HID,
               EA, KV, stream);
        run_mp(FP, HP, x_prp, p_src, mpW_prp + (size_t)i * HID * HID, mpb_prp + i * HID,
               EP, KV, stream);
    }

    // ---- final homo pass: fa ----
    hipMemsetAsync(CTX, 0, (size_t)NA * HID * sizeof(float), stream);
    mail_sum_kernel<<<CDIV(EA * HID, 256), 256, 0, stream>>>(HA, a_dst, CTX, EA);
    last_pass(CTX, FA, f_a, Wlast_a, blast_a, DEGA, FA, Q, out, NA, stream);

    // ---- final homo pass: fp ----
    hipMemsetAsync(CTX, 0, (size_t)NP * HID * sizeof(float), stream);
    mail_sum_kernel<<<CDIV(EP * HID, 256), 256, 0, stream>>>(HP, p_dst, CTX, EP);
    last_pass(CTX, FP, f_p, Wlast_p, blast_p, DEGP, FP, Q,
              out + (size_t)NA * HID, NP, stream);

    // ---- junction pass: fjp (reads pre-update f_junc_a / f_junc_p) ----
    hipMemsetAsync(CTX, 0, (size_t)NP * HID * sizeof(float), stream);
    mail_gather_kernel<<<CDIV(EC * HID, 256), 256, 0, stream>>>(f_junc_a, ap_src, ap_dst, CTX, EC);
    last_pass(CTX, f_junc_p, f_p, Wlast_p, blast_p, DEGAP, f_junc_p, Q,
              out + (size_t)(2 * NA + NP) * HID, NP, stream);

    // ---- junction pass: fja ----
    hipMemsetAsync(CTX, 0, (size_t)NA * HID * sizeof(float), stream);
    mail_gather_kernel<<<CDIV(EC * HID, 256), 256, 0, stream>>>(f_junc_p, pa_src, pa_dst, CTX, EC);
    last_pass(CTX, f_junc_a, f_a, Wlast_a, blast_a, DEGPA, f_junc_a, Q,
              out + (size_t)(NA + NP) * HID, NA, stream);
}